// Round 3
// baseline (406.725 us; speedup 1.0000x reference)
//
#include <hip/hip_runtime.h>

typedef unsigned short u16;
typedef __bf16 bf16x8 __attribute__((ext_vector_type(8)));
typedef float f32x4 __attribute__((ext_vector_type(4)));

// ---------- sizes ----------
#define Bsz 8192

// ws element offsets (u16 elements)
#define OFF_FEAT   0
#define OFF_WCOMB  8388608    // [W_al (512x1024) | W_ol (1536x1024)]
#define OFF_WIN    10485760   // 1536x512
#define OFF_WOUT   11272192   // 512x512
#define OFF_WAH    11534336   // 512x1024
#define OFF_WOH    12058624   // 3x512x512
#define OFF_LAT    12845056   // B x 2048 : [agent_latent | opp0 | opp1 | opp2]
#define OFF_Q      29622272   // B x 512
#define OFF_KV     33816576   // 3 x B x 1024 : [k | v]
#define OFF_ATT    58982400   // B x 512
#define OFF_AO     63176704   // B x 512 (attn_out)
#define OFF_AGH    67371008   // B x 512
#define OFF_OPH    71565312   // 3 x B x 512

// d_out offsets (fp32 elements)
#define OUT_AP 0
#define OUT_AV 49152
#define OUT_OP 57344
#define OUT_OV 204800
#define OUT_IN 229376

__device__ __forceinline__ u16 f2bf(float f) {
  return __builtin_bit_cast(u16, (__bf16)f);
}
__device__ __forceinline__ float bf2f(u16 u) {
  return (float)__builtin_bit_cast(__bf16, u);
}

__device__ __forceinline__ void gload16(const u16* g, u16* s) {
  __builtin_amdgcn_global_load_lds(
      (const __attribute__((address_space(1))) unsigned int*)g,
      (__attribute__((address_space(3))) unsigned int*)s, 16, 0, 0);
}

// ---------- fp32 -> bf16 conversion (order: feat, W_al, W_ol, W_in, W_out, W_ah, W_oh) ----------
#define CV_E0 2097152
#define CV_E1 2228224
#define CV_E2 2621440
#define CV_E3 2818048
#define CV_E4 2883584
#define CV_E5 3014656
#define CV_E6 3211264
__global__ __launch_bounds__(256) void convert_all(
    const float* __restrict__ f, const float* __restrict__ wal,
    const float* __restrict__ wol, const float* __restrict__ win,
    const float* __restrict__ wout, const float* __restrict__ wah,
    const float* __restrict__ woh, u16* __restrict__ dst) {
  int i = blockIdx.x * 256 + threadIdx.x;
  if (i >= CV_E6) return;
  const float* src;
  int base;
  if (i < CV_E0)      { src = f;    base = 0; }
  else if (i < CV_E1) { src = wal;  base = CV_E0; }
  else if (i < CV_E2) { src = wol;  base = CV_E1; }
  else if (i < CV_E3) { src = win;  base = CV_E2; }
  else if (i < CV_E4) { src = wout; base = CV_E3; }
  else if (i < CV_E5) { src = wah;  base = CV_E4; }
  else                { src = woh;  base = CV_E5; }
  float4 v = ((const float4*)src)[i - base];
  ushort4 o;
  o.x = f2bf(v.x); o.y = f2bf(v.y); o.z = f2bf(v.z); o.w = f2bf(v.w);
  ((ushort4*)dst)[i] = o;
}

// ---------- bf16 GEMM v2 ----------
// C[m,n] = act((sum_k A'[m,k]*Bw[n,k] + bias[n]) * scale)
// A' rows: k < ksplit from A (lda), k >= ksplit from A2 (lda2).
// Tile 128x128, BK=32, 4 waves in 2x2. Fragment-ordered LDS staging
// (conflict-free), operand-swapped MFMA so each lane owns 4 consecutive
// cols -> ushort4 stores. 1-D grid with XCD-aware swizzle:
//   xcd = flat&7, s = flat>>3, x = s&(nx-1), yz = ((s>>nxsh)<<3)|xcd
template <bool ELU>
__global__ __launch_bounds__(256) void gemm_v2(
    const u16* __restrict__ A, const u16* __restrict__ A2,
    const u16* __restrict__ Bw, u16* __restrict__ C,
    const float* __restrict__ bias, const float* __restrict__ bias2,
    int K, int ksplit, int bsplit, int lda, int lda2, int ldb, int ldc,
    long sAz, long sBz, long sCz, int sbz, float scale, int nxsh) {
  __shared__ __align__(16) u16 S[8192];  // A frags 0..4095, B frags 4096..8191
  const int wave = threadIdx.x >> 6, lane = threadIdx.x & 63;
  const int l15 = lane & 15, l4 = lane >> 4;

  // swizzled tile decode (ny == 64 always)
  const int flat = blockIdx.x;
  const int xcd = flat & 7, s = flat >> 3;
  const int x = s & ((1 << nxsh) - 1);
  const int yz = ((s >> nxsh) << 3) | xcd;
  const int y = yz & 63, z = yz >> 6;
  const int tM = y * 128, tN = x * 128;

  A  += (size_t)z * sAz;
  A2 += (size_t)z * sAz;   // split-A only used with z=0; harmless
  Bw += (size_t)z * sBz;
  C  += (size_t)z * sCz;
  bias  += (size_t)z * sbz;
  bias2 += (size_t)z * sbz;

  // staging role: waves 0,1 stage A-half (wave), waves 2,3 stage B-half (wave-2)
  const bool isA = wave < 2;
  const int half = isA ? wave : wave - 2;
  const int kch = l4 * 8;
  const u16* p1[4];
  const u16* p2[4];
  u16* dst[4];
#pragma unroll
  for (int t = 0; t < 4; ++t) {
    int rowt = (isA ? tM : tN) + half * 64 + t * 16 + l15;
    if (isA) {
      p1[t] = A + (size_t)rowt * lda + kch;
      p2[t] = A2 + ((long)rowt * lda2 + kch - ksplit);
      dst[t] = &S[(half * 4 + t) * 512];
    } else {
      p1[t] = Bw + (size_t)rowt * ldb + kch;
      p2[t] = p1[t];
      dst[t] = &S[4096 + (half * 4 + t) * 512];
    }
  }
  const int kspl_eff = isA ? ksplit : (1 << 30);

  const int wr = wave >> 1, wc = wave & 1;
  f32x4 acc[4][4];
#pragma unroll
  for (int i = 0; i < 4; i++)
#pragma unroll
    for (int j = 0; j < 4; j++) acc[i][j] = (f32x4){0.f, 0.f, 0.f, 0.f};

  for (int k0 = 0; k0 < K; k0 += 32) {
    __syncthreads();
    const bool first = k0 < kspl_eff;
#pragma unroll
    for (int t = 0; t < 4; ++t)
      gload16((first ? p1[t] : p2[t]) + k0, dst[t]);
    __syncthreads();
    bf16x8 af[4], bfr[4];
#pragma unroll
    for (int mi = 0; mi < 4; mi++)
      af[mi] = *(const bf16x8*)&S[(wr * 4 + mi) * 512 + lane * 8];
#pragma unroll
    for (int ni = 0; ni < 4; ni++)
      bfr[ni] = *(const bf16x8*)&S[4096 + (wc * 4 + ni) * 512 + lane * 8];
#pragma unroll
    for (int mi = 0; mi < 4; mi++)
#pragma unroll
      for (int ni = 0; ni < 4; ni++)
        acc[mi][ni] = __builtin_amdgcn_mfma_f32_16x16x32_bf16(bfr[ni], af[mi], acc[mi][ni], 0, 0, 0);
  }

  // epilogue: lane owns row = tM+wr*64+mi*16+l15, cols col0..col0+3
#pragma unroll
  for (int mi = 0; mi < 4; mi++) {
    const int row = tM + wr * 64 + mi * 16 + l15;
    u16* crow = C + (size_t)row * ldc;
#pragma unroll
    for (int ni = 0; ni < 4; ni++) {
      const int col0 = tN + wc * 64 + ni * 16 + l4 * 4;
      const float* bp = (col0 < bsplit) ? bias + col0 : bias2 + (col0 - bsplit);
      float4 bv = *(const float4*)bp;
      f32x4 a = acc[mi][ni];
      float v0 = (a[0] + bv.x) * scale;
      float v1 = (a[1] + bv.y) * scale;
      float v2 = (a[2] + bv.z) * scale;
      float v3 = (a[3] + bv.w) * scale;
      if (ELU) {
        v0 = v0 > 0.f ? v0 : (__expf(v0) - 1.f);
        v1 = v1 > 0.f ? v1 : (__expf(v1) - 1.f);
        v2 = v2 > 0.f ? v2 : (__expf(v2) - 1.f);
        v3 = v3 > 0.f ? v3 : (__expf(v3) - 1.f);
      }
      ushort4 st;
      st.x = f2bf(v0); st.y = f2bf(v1); st.z = f2bf(v2); st.w = f2bf(v3);
      *(ushort4*)(crow + col0) = st;
    }
  }
}

// ---------- attention: scores/softmax over O=3, attn out + influences ----------
__global__ __launch_bounds__(256) void attn_kernel(
    const u16* __restrict__ q, const u16* __restrict__ kv,
    u16* __restrict__ attn, float* __restrict__ influ) {
  const int wave = threadIdx.x >> 6, lane = threadIdx.x & 63;
  const int b = blockIdx.x * 4 + wave;
  const size_t qb = (size_t)b * 512;
  float wacc0 = 0.f, wacc1 = 0.f, wacc2 = 0.f;
#pragma unroll
  for (int h = 0; h < 4; ++h) {
    const int off = h * 128 + lane * 2;
    ushort2 qu = *(const ushort2*)(q + qb + off);
    float qx = bf2f(qu.x), qy = bf2f(qu.y);
    float s[3];
#pragma unroll
    for (int o = 0; o < 3; ++o) {
      ushort2 ku = *(const ushort2*)(kv + (size_t)o * (Bsz * 1024) + (size_t)b * 1024 + off);
      float p = qx * bf2f(ku.x) + qy * bf2f(ku.y);
#pragma unroll
      for (int d = 32; d; d >>= 1) p += __shfl_xor(p, d, 64);
      s[o] = p;
    }
    float m = fmaxf(s[0], fmaxf(s[1], s[2]));
    float e0 = __expf(s[0] - m), e1 = __expf(s[1] - m), e2 = __expf(s[2] - m);
    float inv = 1.f / (e0 + e1 + e2);
    float w0 = e0 * inv, w1 = e1 * inv, w2 = e2 * inv;
    wacc0 += w0; wacc1 += w1; wacc2 += w2;
    float ax = 0.f, ay = 0.f;
#pragma unroll
    for (int o = 0; o < 3; ++o) {
      float w = (o == 0) ? w0 : (o == 1) ? w1 : w2;
      ushort2 vu = *(const ushort2*)(kv + (size_t)o * (Bsz * 1024) + (size_t)b * 1024 + 512 + off);
      ax += w * bf2f(vu.x);
      ay += w * bf2f(vu.y);
    }
    ushort2 st; st.x = f2bf(ax); st.y = f2bf(ay);
    *(ushort2*)(attn + qb + off) = st;
  }
  if (lane == 0) {
    influ[b * 3 + 0] = wacc0 * 0.25f;
    influ[b * 3 + 1] = wacc1 * 0.25f;
    influ[b * 3 + 2] = wacc2 * 0.25f;
  }
}

// ---------- final heads: 28 length-512 dots per row ----------
// kq = lane&7 owns a 64-elem K slice, r = lane>>3 owns a row.
__global__ __launch_bounds__(256) void heads_kernel(
    const u16* __restrict__ ah, const u16* __restrict__ oh,
    const float* __restrict__ Wap, const float* __restrict__ bap,
    const float* __restrict__ Wav, const float* __restrict__ bav,
    const float* __restrict__ Wop, const float* __restrict__ bop,
    const float* __restrict__ Wov, const float* __restrict__ bov,
    float* __restrict__ out) {
  __shared__ float sW[14336];
  for (int i = threadIdx.x; i < 14336; i += 256) {
    int s = i / 3584, rem = i - s * 3584;
    float v;
    if (s == 0) {
      v = (rem < 3072) ? Wap[rem] : Wav[rem - 3072];
    } else {
      int o = s - 1;
      v = (rem < 3072) ? Wop[o * 3072 + rem] : Wov[o * 512 + (rem - 3072)];
    }
    sW[i] = v;
  }
  __syncthreads();
  const int wave = threadIdx.x >> 6, lane = threadIdx.x & 63;
  const int kq = lane & 7, r = lane >> 3;
  const int b = blockIdx.x * 32 + wave * 8 + r;

  const u16* srcs[4] = {ah + (size_t)b * 512,
                        oh + (size_t)b * 512,
                        oh + (size_t)(Bsz + b) * 512,
                        oh + (size_t)(2 * Bsz + b) * 512};
  bf16x8 a[4][8];
#pragma unroll
  for (int s = 0; s < 4; s++)
#pragma unroll
    for (int c = 0; c < 8; c++)
      a[s][c] = *(const bf16x8*)(srcs[s] + c * 64 + kq * 8);

#pragma unroll
  for (int s = 0; s < 4; s++) {
#pragma unroll
    for (int p = 0; p < 7; p++) {
      const float* w = &sW[s * 3584 + p * 512 + kq * 8];
      float acc = 0.f;
#pragma unroll
      for (int c = 0; c < 8; c++) {
#pragma unroll
        for (int j = 0; j < 8; j++)
          acc += (float)a[s][c][j] * w[c * 64 + j];
      }
      acc += __shfl_xor(acc, 1, 64);
      acc += __shfl_xor(acc, 2, 64);
      acc += __shfl_xor(acc, 4, 64);
      if (kq == p) {
        if (s == 0) {
          if (p < 6) out[OUT_AP + b * 6 + p] = acc + bap[p];
          else       out[OUT_AV + b] = acc + bav[0];
        } else {
          int o = s - 1;
          if (p < 6) out[OUT_OP + b * 18 + o * 6 + p] = acc + bop[o * 6 + p];
          else       out[OUT_OV + b * 3 + o] = acc + bov[o];
        }
      }
    }
  }
}

extern "C" void kernel_launch(void* const* d_in, const int* in_sizes, int n_in,
                              void* d_out, int out_size, void* d_ws, size_t ws_size,
                              hipStream_t stream) {
  (void)in_sizes; (void)n_in; (void)out_size; (void)ws_size;
  const float* f     = (const float*)d_in[0];
  const float* W_al  = (const float*)d_in[1];
  const float* b_al  = (const float*)d_in[2];
  const float* W_in  = (const float*)d_in[3];
  const float* b_in  = (const float*)d_in[4];
  const float* W_out = (const float*)d_in[5];
  const float* b_out = (const float*)d_in[6];
  const float* W_ah  = (const float*)d_in[7];
  const float* b_ah  = (const float*)d_in[8];
  const float* W_ap  = (const float*)d_in[9];
  const float* b_ap  = (const float*)d_in[10];
  const float* W_av  = (const float*)d_in[11];
  const float* b_av  = (const float*)d_in[12];
  const float* W_ol  = (const float*)d_in[13];
  const float* b_ol  = (const float*)d_in[14];
  const float* W_oh  = (const float*)d_in[15];
  const float* b_oh  = (const float*)d_in[16];
  const float* W_op  = (const float*)d_in[17];
  const float* b_op  = (const float*)d_in[18];
  const float* W_ov  = (const float*)d_in[19];
  const float* b_ov  = (const float*)d_in[20];
  float* out = (float*)d_out;
  u16* ws = (u16*)d_ws;

  u16* feat  = ws + OFF_FEAT;
  u16* wcomb = ws + OFF_WCOMB;
  u16* win   = ws + OFF_WIN;
  u16* wout  = ws + OFF_WOUT;
  u16* wah   = ws + OFF_WAH;
  u16* woh   = ws + OFF_WOH;
  u16* lat   = ws + OFF_LAT;
  u16* qb    = ws + OFF_Q;
  u16* kvb   = ws + OFF_KV;
  u16* att   = ws + OFF_ATT;
  u16* ao    = ws + OFF_AO;
  u16* agh   = ws + OFF_AGH;
  u16* oph   = ws + OFF_OPH;

  const int BIG = 1 << 30;

  convert_all<<<12544, 256, 0, stream>>>(f, W_al, W_ol, W_in, W_out, W_ah, W_oh, ws);

  // lat = elu(feat @ [W_al;W_ol]^T + [b_al;b_ol])  (B x 2048)
  gemm_v2<true><<<1024, 256, 0, stream>>>(
      feat, feat, wcomb, lat, b_al, b_ol, 1024, BIG, 512,
      1024, 1024, 1024, 2048, 0, 0, 0, 0, 1.f, 4);
  // q = (agent_latent @ Wq^T + bq) / sqrt(128)
  gemm_v2<false><<<256, 256, 0, stream>>>(
      lat, lat, win, qb, b_in, b_in, 512, BIG, BIG,
      2048, 2048, 512, 512, 0, 0, 0, 0, 0.08838834764831845f, 2);
  // kv[z] = opp_lat[z] @ [Wk;Wv]^T + [bk;bv]
  gemm_v2<false><<<1536, 256, 0, stream>>>(
      lat + 512, lat + 512, win + 262144, kvb, b_in + 512, b_in + 512,
      512, BIG, BIG, 2048, 2048, 512, 1024, 512, 0, 8388608, 0, 1.f, 3);

  attn_kernel<<<2048, 256, 0, stream>>>(qb, kvb, att, out + OUT_IN);

  // attn_out = attn @ W_out^T + b_out
  gemm_v2<false><<<256, 256, 0, stream>>>(
      att, att, wout, ao, b_out, b_out, 512, BIG, BIG,
      512, 512, 512, 512, 0, 0, 0, 0, 1.f, 2);
  // agent_head = elu([agent_latent | attn_out] @ W_ah^T + b_ah)  (split-A)
  gemm_v2<true><<<256, 256, 0, stream>>>(
      lat, ao, wah, agh, b_ah, b_ah, 1024, 512, BIG,
      2048, 512, 1024, 512, 0, 0, 0, 0, 1.f, 2);
  // opp_heads[z] = elu(opp_lat[z] @ W_oh[z]^T + b_oh[z])
  gemm_v2<true><<<768, 256, 0, stream>>>(
      lat + 512, lat + 512, woh, oph, b_oh, b_oh, 512, BIG, BIG,
      2048, 2048, 512, 512, 512, 262144, 4194304, 512, 1.f, 2);

  heads_kernel<<<256, 256, 0, stream>>>(agh, oph, W_ap, b_ap, W_av, b_av,
                                        W_op, b_op, W_ov, b_ov, out);
}

// Round 4
// 392.020 us; speedup vs baseline: 1.0375x; 1.0375x over previous
//
#include <hip/hip_runtime.h>

typedef unsigned short u16;
typedef __bf16 bf16x8 __attribute__((ext_vector_type(8)));
typedef float f32x4 __attribute__((ext_vector_type(4)));

#define Bsz 8192
#define BIGI (1 << 30)

// ws element offsets (u16 elements)
#define OFF_FEAT   0
#define OFF_WCOMB  8388608    // [W_al (512x1024) | W_ol (1536x1024)]
#define OFF_WQ     10485760   // 512x512 (W_in rows 0..511)
#define OFF_WOUT   10747904   // 512x512
#define OFF_WAH    11010048   // 512x1024
#define OFF_PACK   11534336   // 3 x 1536x512 : [Wk; Wv; W_oh[z]]
#define OFF_LAT    13893632   // B x 2048 : [agent | opp0 | opp1 | opp2]
#define OFF_Q      30670848   // B x 512 (later reused for agent_head)
#define OFF_KV     34865152   // 3 x B x 1024 : [k | v]
#define OFF_ATT    60030976   // B x 512
#define OFF_AO     64225280   // B x 512
#define OFF_OPH    68419584   // 3 x B x 512

// d_out offsets (fp32 elements)
#define OUT_AP 0
#define OUT_AV 49152
#define OUT_OP 57344
#define OUT_OV 204800
#define OUT_IN 229376

__device__ __forceinline__ u16 f2bf(float f) {
  return __builtin_bit_cast(u16, (__bf16)f);
}
__device__ __forceinline__ float bf2f(u16 u) {
  return (float)__builtin_bit_cast(__bf16, u);
}

__device__ __forceinline__ void gload16(const u16* g, u16* s) {
  __builtin_amdgcn_global_load_lds(
      (const __attribute__((address_space(1))) unsigned int*)g,
      (__attribute__((address_space(3))) unsigned int*)s, 16, 0, 0);
}

// ---------- fp32 -> bf16 conversion + B-pack build ----------
// segments (float4 units): feat, W_al, W_ol, Wq(=W_in rows 0..511), W_out,
// W_ah, pack(3x1536x512 from W_in rows 512..1535 + W_oh[z])
#define CV_E0 2097152
#define CV_E1 2228224
#define CV_E2 2621440
#define CV_E3 2686976
#define CV_E4 2752512
#define CV_E5 2883584
#define CV_E6 3473408
__global__ __launch_bounds__(256) void convert_all(
    const float* __restrict__ f, const float* __restrict__ wal,
    const float* __restrict__ wol, const float* __restrict__ win,
    const float* __restrict__ wout, const float* __restrict__ wah,
    const float* __restrict__ woh, u16* __restrict__ dst) {
  int i = blockIdx.x * 256 + threadIdx.x;
  if (i >= CV_E6) return;
  float4 v;
  if (i < CV_E5) {
    const float* src;
    int base;
    if (i < CV_E0)      { src = f;    base = 0; }
    else if (i < CV_E1) { src = wal;  base = CV_E0; }
    else if (i < CV_E2) { src = wol;  base = CV_E1; }
    else if (i < CV_E3) { src = win;  base = CV_E2; }
    else if (i < CV_E4) { src = wout; base = CV_E3; }
    else                { src = wah;  base = CV_E4; }
    v = ((const float4*)src)[i - base];
  } else {
    // pack: per z, rows 0..1023 = W_in rows 512..1535; rows 1024..1535 = W_oh[z]
    int j = i - CV_E5;
    int z = j / 196608;
    int rem = j - z * 196608;
    int row = rem >> 7, cu = rem & 127;
    if (row < 1024) v = ((const float4*)win)[(512 + row) * 128 + cu];
    else            v = ((const float4*)woh)[z * 65536 + (row - 1024) * 128 + cu];
  }
  ushort4 o;
  o.x = f2bf(v.x); o.y = f2bf(v.y); o.z = f2bf(v.z); o.w = f2bf(v.w);
  ((ushort4*)dst)[i] = o;
}

// ---------- bf16 GEMM v3 ----------
// C[m,n] = act((sum_k A'[m,k]*Bw[n,k] + bias[n]) * scale)
// A' rows: k < ksplit from A (lda), else from A2 (lda2).
// C cols: n < csplit -> C1 (ldc1), else C2 (ldc2). bias split at bsplit.
// ELU applied iff n >= act_split.
// BM in {64,128}, BN=128, BK=32, 4 waves 2x2, wave tile (BM/2)x64.
// Fragment-ordered LDS staging (conflict-free, layout == MFMA operand order).
// Operand-swapped MFMA: lane owns 4 consecutive cols -> ushort4 stores.
// 1-D grid, XCD swizzle: xcd=flat&7, s=flat>>3, x=s%nx, yz=(s/nx)*8+xcd.
template <int BM>
__global__ __launch_bounds__(256) void gemm_v3(
    const u16* __restrict__ A, const u16* __restrict__ A2,
    const u16* __restrict__ Bw,
    u16* __restrict__ C1, u16* __restrict__ C2, int csplit, int ldc1, int ldc2,
    const float* __restrict__ bias1, const float* __restrict__ bias2, int bsplit,
    int K, int ksplit, int lda, int lda2, int ldb,
    long sAz, long sBz, long sC1z, long sC2z, int sb1z, int sb2z,
    float scale, int act_split, int nx) {
  constexpr int nA = BM / 16;          // A frags (1 KB each)
  constexpr int NFR = nA + 8;          // + 8 B frags
  constexpr int FPW = NFR / 4;         // frags per wave
  constexpr int MI = BM / 32;
  constexpr int SB = nA * 512;
  __shared__ __align__(16) u16 S[NFR * 512];
  const int wave = threadIdx.x >> 6, lane = threadIdx.x & 63;
  const int l15 = lane & 15, l4 = lane >> 4;

  const int flat = blockIdx.x;
  const int xcd = flat & 7;
  const unsigned s = flat >> 3;
  const int x = s % nx;
  const int yz = (s / nx) * 8 + xcd;
  constexpr int NY = 8192 / BM;
  const int y = yz & (NY - 1), z = yz / NY;
  const int tM = y * BM, tN = x * 128;

  A  += (size_t)z * sAz;
  A2 += (size_t)z * sAz;
  Bw += (size_t)z * sBz;
  const u16* p1[FPW];
  const u16* p2[FPW];
  u16* dst[FPW];
  int kspl[FPW];
  const int kch = l4 * 8;
#pragma unroll
  for (int t = 0; t < FPW; ++t) {
    const int fr = wave * FPW + t;
    if (fr < nA) {
      const int row = tM + fr * 16 + l15;
      p1[t] = A + (size_t)row * lda + kch;
      p2[t] = A2 + ((long)row * lda2 + kch - ksplit);
      dst[t] = &S[fr * 512];
      kspl[t] = ksplit;
    } else {
      const int g = fr - nA;
      const int row = tN + g * 16 + l15;
      p1[t] = Bw + (size_t)row * ldb + kch;
      p2[t] = p1[t];
      dst[t] = &S[SB + g * 512];
      kspl[t] = BIGI;
    }
  }

  const int wr = wave >> 1, wc = wave & 1;
  f32x4 acc[MI][4];
#pragma unroll
  for (int i = 0; i < MI; i++)
#pragma unroll
    for (int j = 0; j < 4; j++) acc[i][j] = (f32x4){0.f, 0.f, 0.f, 0.f};

  for (int k0 = 0; k0 < K; k0 += 32) {
    __syncthreads();
#pragma unroll
    for (int t = 0; t < FPW; ++t)
      gload16((k0 < kspl[t] ? p1[t] : p2[t]) + k0, dst[t]);
    __syncthreads();
    bf16x8 af[MI], bfr[4];
#pragma unroll
    for (int mi = 0; mi < MI; mi++)
      af[mi] = *(const bf16x8*)&S[(wr * MI + mi) * 512 + lane * 8];
#pragma unroll
    for (int ni = 0; ni < 4; ni++)
      bfr[ni] = *(const bf16x8*)&S[SB + (wc * 4 + ni) * 512 + lane * 8];
#pragma unroll
    for (int mi = 0; mi < MI; mi++)
#pragma unroll
      for (int ni = 0; ni < 4; ni++)
        acc[mi][ni] = __builtin_amdgcn_mfma_f32_16x16x32_bf16(bfr[ni], af[mi], acc[mi][ni], 0, 0, 0);
  }

#pragma unroll
  for (int mi = 0; mi < MI; mi++) {
    const int row = tM + wr * (BM / 2) + mi * 16 + l15;
#pragma unroll
    for (int ni = 0; ni < 4; ni++) {
      const int col0 = tN + wc * 64 + ni * 16 + l4 * 4;
      const float* bp = (col0 < bsplit) ? bias1 + (size_t)z * sb1z + col0
                                        : bias2 + (size_t)z * sb2z + (col0 - bsplit);
      float4 bv = *(const float4*)bp;
      f32x4 a = acc[mi][ni];
      float v0 = (a[0] + bv.x) * scale;
      float v1 = (a[1] + bv.y) * scale;
      float v2 = (a[2] + bv.z) * scale;
      float v3 = (a[3] + bv.w) * scale;
      if (col0 >= act_split) {
        v0 = v0 > 0.f ? v0 : (__expf(v0) - 1.f);
        v1 = v1 > 0.f ? v1 : (__expf(v1) - 1.f);
        v2 = v2 > 0.f ? v2 : (__expf(v2) - 1.f);
        v3 = v3 > 0.f ? v3 : (__expf(v3) - 1.f);
      }
      ushort4 st;
      st.x = f2bf(v0); st.y = f2bf(v1); st.z = f2bf(v2); st.w = f2bf(v3);
      u16* cp = (col0 < csplit)
                    ? C1 + (size_t)z * sC1z + (size_t)row * ldc1 + col0
                    : C2 + (size_t)z * sC2z + (size_t)row * ldc2 + (col0 - csplit);
      *(ushort4*)cp = st;
    }
  }
}

// ---------- attention ----------
__global__ __launch_bounds__(256) void attn_kernel(
    const u16* __restrict__ q, const u16* __restrict__ kv,
    u16* __restrict__ attn, float* __restrict__ influ) {
  const int wave = threadIdx.x >> 6, lane = threadIdx.x & 63;
  const int b = blockIdx.x * 4 + wave;
  const size_t qb = (size_t)b * 512;
  float wacc0 = 0.f, wacc1 = 0.f, wacc2 = 0.f;
#pragma unroll
  for (int h = 0; h < 4; ++h) {
    const int off = h * 128 + lane * 2;
    ushort2 qu = *(const ushort2*)(q + qb + off);
    float qx = bf2f(qu.x), qy = bf2f(qu.y);
    float s[3];
#pragma unroll
    for (int o = 0; o < 3; ++o) {
      ushort2 ku = *(const ushort2*)(kv + (size_t)o * (Bsz * 1024) + (size_t)b * 1024 + off);
      float p = qx * bf2f(ku.x) + qy * bf2f(ku.y);
#pragma unroll
      for (int d = 32; d; d >>= 1) p += __shfl_xor(p, d, 64);
      s[o] = p;
    }
    float m = fmaxf(s[0], fmaxf(s[1], s[2]));
    float e0 = __expf(s[0] - m), e1 = __expf(s[1] - m), e2 = __expf(s[2] - m);
    float inv = 1.f / (e0 + e1 + e2);
    float w0 = e0 * inv, w1 = e1 * inv, w2 = e2 * inv;
    wacc0 += w0; wacc1 += w1; wacc2 += w2;
    float ax = 0.f, ay = 0.f;
#pragma unroll
    for (int o = 0; o < 3; ++o) {
      float w = (o == 0) ? w0 : (o == 1) ? w1 : w2;
      ushort2 vu = *(const ushort2*)(kv + (size_t)o * (Bsz * 1024) + (size_t)b * 1024 + 512 + off);
      ax += w * bf2f(vu.x);
      ay += w * bf2f(vu.y);
    }
    ushort2 st; st.x = f2bf(ax); st.y = f2bf(ay);
    *(ushort2*)(attn + qb + off) = st;
  }
  if (lane == 0) {
    influ[b * 3 + 0] = wacc0 * 0.25f;
    influ[b * 3 + 1] = wacc1 * 0.25f;
    influ[b * 3 + 2] = wacc2 * 0.25f;
  }
}

// ---------- final heads ----------
__global__ __launch_bounds__(256) void heads_kernel(
    const u16* __restrict__ ah, const u16* __restrict__ oh,
    const float* __restrict__ Wap, const float* __restrict__ bap,
    const float* __restrict__ Wav, const float* __restrict__ bav,
    const float* __restrict__ Wop, const float* __restrict__ bop,
    const float* __restrict__ Wov, const float* __restrict__ bov,
    float* __restrict__ out) {
  __shared__ float sW[14336];
  for (int i = threadIdx.x; i < 14336; i += 256) {
    int s = i / 3584, rem = i - s * 3584;
    float v;
    if (s == 0) {
      v = (rem < 3072) ? Wap[rem] : Wav[rem - 3072];
    } else {
      int o = s - 1;
      v = (rem < 3072) ? Wop[o * 3072 + rem] : Wov[o * 512 + (rem - 3072)];
    }
    sW[i] = v;
  }
  __syncthreads();
  const int wave = threadIdx.x >> 6, lane = threadIdx.x & 63;
  const int kq = lane & 7, r = lane >> 3;
  const int b = blockIdx.x * 32 + wave * 8 + r;

  const u16* srcs[4] = {ah + (size_t)b * 512,
                        oh + (size_t)b * 512,
                        oh + (size_t)(Bsz + b) * 512,
                        oh + (size_t)(2 * Bsz + b) * 512};
  bf16x8 a[4][8];
#pragma unroll
  for (int s = 0; s < 4; s++)
#pragma unroll
    for (int c = 0; c < 8; c++)
      a[s][c] = *(const bf16x8*)(srcs[s] + c * 64 + kq * 8);

#pragma unroll
  for (int s = 0; s < 4; s++) {
#pragma unroll
    for (int p = 0; p < 7; p++) {
      const float* w = &sW[s * 3584 + p * 512 + kq * 8];
      float acc = 0.f;
#pragma unroll
      for (int c = 0; c < 8; c++) {
#pragma unroll
        for (int j = 0; j < 8; j++)
          acc += (float)a[s][c][j] * w[c * 64 + j];
      }
      acc += __shfl_xor(acc, 1, 64);
      acc += __shfl_xor(acc, 2, 64);
      acc += __shfl_xor(acc, 4, 64);
      if (kq == p) {
        if (s == 0) {
          if (p < 6) out[OUT_AP + b * 6 + p] = acc + bap[p];
          else       out[OUT_AV + b] = acc + bav[0];
        } else {
          int o = s - 1;
          if (p < 6) out[OUT_OP + b * 18 + o * 6 + p] = acc + bop[o * 6 + p];
          else       out[OUT_OV + b * 3 + o] = acc + bov[o];
        }
      }
    }
  }
}

extern "C" void kernel_launch(void* const* d_in, const int* in_sizes, int n_in,
                              void* d_out, int out_size, void* d_ws, size_t ws_size,
                              hipStream_t stream) {
  (void)in_sizes; (void)n_in; (void)out_size; (void)ws_size;
  const float* f     = (const float*)d_in[0];
  const float* W_al  = (const float*)d_in[1];
  const float* b_al  = (const float*)d_in[2];
  const float* W_in  = (const float*)d_in[3];
  const float* b_in  = (const float*)d_in[4];
  const float* W_out = (const float*)d_in[5];
  const float* b_out = (const float*)d_in[6];
  const float* W_ah  = (const float*)d_in[7];
  const float* b_ah  = (const float*)d_in[8];
  const float* W_ap  = (const float*)d_in[9];
  const float* b_ap  = (const float*)d_in[10];
  const float* W_av  = (const float*)d_in[11];
  const float* b_av  = (const float*)d_in[12];
  const float* W_ol  = (const float*)d_in[13];
  const float* b_ol  = (const float*)d_in[14];
  const float* W_oh  = (const float*)d_in[15];
  const float* b_oh  = (const float*)d_in[16];
  const float* W_op  = (const float*)d_in[17];
  const float* b_op  = (const float*)d_in[18];
  const float* W_ov  = (const float*)d_in[19];
  const float* b_ov  = (const float*)d_in[20];
  float* out = (float*)d_out;
  u16* ws = (u16*)d_ws;

  u16* feat  = ws + OFF_FEAT;
  u16* wcomb = ws + OFF_WCOMB;
  u16* wq    = ws + OFF_WQ;
  u16* wout  = ws + OFF_WOUT;
  u16* wah   = ws + OFF_WAH;
  u16* pack  = ws + OFF_PACK;
  u16* lat   = ws + OFF_LAT;
  u16* qb    = ws + OFF_Q;
  u16* kvb   = ws + OFF_KV;
  u16* att   = ws + OFF_ATT;
  u16* ao    = ws + OFF_AO;
  u16* agh   = ws + OFF_Q;   // reuse q's slot after attention
  u16* oph   = ws + OFF_OPH;

  convert_all<<<13568, 256, 0, stream>>>(f, W_al, W_ol, W_in, W_out, W_ah, W_oh, ws);

  // lat = elu(feat @ [W_al;W_ol]^T + [b_al;b_ol])  (B x 2048)
  gemm_v3<128><<<1024, 256, 0, stream>>>(
      feat, feat, wcomb, lat, lat, BIGI, 2048, 2048,
      b_al, b_ol, 512, 1024, BIGI, 1024, 1024, 1024,
      0, 0, 0, 0, 0, 0, 1.f, 0, 16);
  // q = (agent_latent @ Wq^T + bq) / sqrt(128)
  gemm_v3<64><<<512, 256, 0, stream>>>(
      lat, lat, wq, qb, qb, BIGI, 512, 512,
      b_in, b_in, BIGI, 512, BIGI, 2048, 2048, 512,
      0, 0, 0, 0, 0, 0, 0.08838834764831845f, BIGI, 4);
  // merged kv + opp_heads: A = opp_lat[z], B = [Wk;Wv;W_oh[z]] (N=1536)
  // cols 0..1023 -> kvb[z] (no act), cols 1024..1535 -> oph[z] (ELU)
  gemm_v3<128><<<2304, 256, 0, stream>>>(
      lat + 512, lat + 512, pack, kvb, oph, 1024, 1024, 512,
      b_in + 512, b_oh, 1024, 512, BIGI, 2048, 2048, 512,
      512, 786432, 8388608, 4194304, 0, 512, 1.f, 1024, 12);

  attn_kernel<<<2048, 256, 0, stream>>>(qb, kvb, att, out + OUT_IN);

  // attn_out = attn @ W_out^T + b_out
  gemm_v3<64><<<512, 256, 0, stream>>>(
      att, att, wout, ao, ao, BIGI, 512, 512,
      b_out, b_out, BIGI, 512, BIGI, 512, 512, 512,
      0, 0, 0, 0, 0, 0, 1.f, BIGI, 4);
  // agent_head = elu([agent_latent | attn_out] @ W_ah^T + b_ah)  (split-A)
  gemm_v3<64><<<512, 256, 0, stream>>>(
      lat, ao, wah, agh, agh, BIGI, 512, 512,
      b_ah, b_ah, BIGI, 1024, 512, 2048, 512, 1024,
      0, 0, 0, 0, 0, 0, 1.f, 0, 4);

  heads_kernel<<<256, 256, 0, stream>>>(agh, oph, W_ap, b_ap, W_av, b_av,
                                        W_op, b_op, W_ov, b_ov, out);
}